// Round 8
// baseline (271.554 us; speedup 1.0000x reference)
//
#include <hip/hip_runtime.h>
#include <hip/hip_bf16.h>

#define BATCH   4
#define NBOX    8192
#define BLOCK   256
#define TSZ     256                  // tile size (rows & cols)
#define NT      (NBOX / TSZ)         // 32 tiles per batch
#define NPAIRS  (NT * (NT + 1) / 2)  // 528 tile-pairs per batch

__device__ __forceinline__ float bf2f(unsigned short u) {
    union { unsigned int i; float f; } c;
    c.i = ((unsigned int)u) << 16;
    return c.f;
}

__device__ __forceinline__ bool box_plausible(float x1, float y1, float x2, float y2) {
    bool ok = (x1 == x1) && (y1 == y1) && (x2 == x2) && (y2 == y2);
    ok = ok && fabsf(x1) < 1e4f && fabsf(y1) < 1e4f && fabsf(x2) < 1e4f && fabsf(y2) < 1e4f;
    ok = ok && x1 >= -1.0f && x1 <= 300.0f && y1 >= -1.0f && y1 <= 300.0f;
    const float w = x2 - x1, h = y2 - y1;
    ok = ok && w >= -0.1f && w <= 80.0f && h >= -0.1f && h <= 80.0f;
    return ok;
}

// Wave-redundant dtype probe; all waves deterministically agree. true -> f32.
__device__ __forceinline__ bool wave_probe_is_f32(const void* boxes_raw) {
    const int lane = threadIdx.x & 63;
    const float* bf = (const float*)boxes_raw;
    const bool okf = box_plausible(bf[lane * 4 + 0], bf[lane * 4 + 1],
                                   bf[lane * 4 + 2], bf[lane * 4 + 3]);
    const unsigned short* bh = (const unsigned short*)boxes_raw;
    const bool okh = box_plausible(bf2f(bh[lane * 4 + 0]), bf2f(bh[lane * 4 + 1]),
                                   bf2f(bh[lane * 4 + 2]), bf2f(bh[lane * 4 + 3]));
    const unsigned long long mf = __ballot(okf);
    const unsigned long long mh = __ballot(okh);
    return __popcll(mf) >= __popcll(mh);
}

__device__ __forceinline__ float4 load_box(const void* boxes_raw, size_t idx, bool isf32) {
    if (isf32) {
        return reinterpret_cast<const float4*>(boxes_raw)[idx];
    } else {
        const ushort4 u = reinterpret_cast<const ushort4*>(boxes_raw)[idx];
        return make_float4(bf2f(u.x), bf2f(u.y), bf2f(u.z), bf2f(u.w));
    }
}

__device__ __forceinline__ float load_score(const void* scores_raw, size_t idx, bool isf32) {
    return isf32 ? ((const float*)scores_raw)[idx]
                 : bf2f(((const unsigned short*)scores_raw)[idx]);
}

// exp(-iou/0.5) = exp2(iou * (-2 log2 e)); arg in [-2.886, 0] -> raw v_exp ok
#define CEXP (-2.8853900817779268f)

__device__ __forceinline__ float pair_weight(
    float ix1, float iy1, float ix2, float iy2, float iarea,
    const float4& bj, float jarea)
{
    float w = fminf(ix2, bj.z) - fmaxf(ix1, bj.x);
    float h = fminf(iy2, bj.w) - fmaxf(iy1, bj.y);
    w = fmaxf(w, 0.0f);
    h = fmaxf(h, 0.0f);
    const float inter = w * h;
    const float uni   = iarea + jarea - inter;          // >= ~1 always
    const float arg   = (CEXP * inter) * __builtin_amdgcn_rcpf(uni);
    return __builtin_amdgcn_exp2f(arg);
}

// adjusted[b][i] = sum_j exp(-2*iou(i,j)) * scores[b][j], exploiting symmetry.
// One block per tile-pair (it <= jt). Each thread owns 4 rows {k*64+lane} in
// registers; wave wv rotates through its exclusive col window [wv*64,+64).
// Column side accumulates via fire-and-forget ds_add_f32 (LDS atomicAdd with
// unused return): no lgkmcnt dependency in the wave's critical path (the
// round-7 shfl hand-off stalled in-order issue on LDS-return latency).
__global__ __launch_bounds__(BLOCK, 4) void soft_nms_adj_kernel(
    const void* __restrict__ boxes_raw,   // (B,N,4) f32 or bf16
    const void* __restrict__ scores_raw,  // (B,N)   f32 or bf16
    float* __restrict__ adj)              // (B,N)   f32, zeroed
{
    __shared__ float4 sbox[TSZ];          // j-tile: x1,y1,x2,y2
    __shared__ float2 sas[TSZ];           // j-tile: area, score
    __shared__ float  scol[TSZ];          // column partials (ds_add)
    __shared__ float  srow[TSZ];          // row partials (ds_add at end)

    const int bid = blockIdx.x;
    const int b   = bid / NPAIRS;
    int p = bid % NPAIRS;
    int it = 0;
    while (p >= NT - it) { p -= NT - it; it++; }   // triangular decode
    const int jt = it + p;

    const int tid  = threadIdx.x;
    const int lane = tid & 63;
    const int wv   = tid >> 6;

    const bool isf32 = wave_probe_is_f32(boxes_raw);
    const size_t base = (size_t)b * NBOX;

    // stage j-tile into LDS + zero the partial arrays
    {
        const int jg = jt * TSZ + tid;
        const float4 uj = load_box(boxes_raw, base + jg, isf32);
        sbox[tid] = uj;
        sas[tid]  = make_float2((uj.z - uj.x) * (uj.w - uj.y),
                                load_score(scores_raw, base + jg, isf32));
        scol[tid] = 0.0f;
        srow[tid] = 0.0f;
    }

    // rows: thread owns rows {k*64 + lane} of the i-tile (same set in every wave)
    float rx1[4], ry1[4], rx2[4], ry2[4], rar[4], rsc[4], accr[4];
#pragma unroll
    for (int k = 0; k < 4; k++) {
        const int ig = it * TSZ + k * 64 + lane;
        const float4 ui = load_box(boxes_raw, base + ig, isf32);
        rx1[k] = ui.x; ry1[k] = ui.y; rx2[k] = ui.z; ry2[k] = ui.w;
        rar[k] = (ui.z - ui.x) * (ui.w - ui.y);
        rsc[k] = load_score(scores_raw, base + ig, isf32);
        accr[k] = 0.0f;
    }

    __syncthreads();

    const int wvbase = wv * 64;

    if (it == jt) {
        // diagonal: full ordered pairs, row side only (includes i==j)
        int rot = lane;
#pragma unroll 4
        for (int t = 0; t < 64; t++) {
            const int idx = wvbase + rot;
            rot = (rot + 1) & 63;
            const float4 bj = sbox[idx];
            const float2 as = sas[idx];
#pragma unroll
            for (int k = 0; k < 4; k++) {
                const float e = pair_weight(rx1[k], ry1[k], rx2[k], ry2[k], rar[k], bj, as.x);
                accr[k] = fmaf(e, as.y, accr[k]);
            }
        }
    } else {
        // off-diagonal: symmetric; col side scattered via ds_add_f32 (no return)
        int rot = lane;
#pragma unroll 4
        for (int t = 0; t < 64; t++) {
            const int idx = wvbase + rot;        // permutation: conflict-free
            rot = (rot + 1) & 63;
            const float4 bj = sbox[idx];
            const float2 as = sas[idx];
            const float e0 = pair_weight(rx1[0], ry1[0], rx2[0], ry2[0], rar[0], bj, as.x);
            const float e1 = pair_weight(rx1[1], ry1[1], rx2[1], ry2[1], rar[1], bj, as.x);
            const float e2 = pair_weight(rx1[2], ry1[2], rx2[2], ry2[2], rar[2], bj, as.x);
            const float e3 = pair_weight(rx1[3], ry1[3], rx2[3], ry2[3], rar[3], bj, as.x);
            accr[0] = fmaf(e0, as.y, accr[0]);
            accr[1] = fmaf(e1, as.y, accr[1]);
            accr[2] = fmaf(e2, as.y, accr[2]);
            accr[3] = fmaf(e3, as.y, accr[3]);
            const float c = fmaf(e0, rsc[0], fmaf(e1, rsc[1], fmaf(e2, rsc[2], e3 * rsc[3])));
            atomicAdd(&scol[idx], c);            // ds_add_f32, fire-and-forget
        }
    }

    // combine row partials across waves (one LDS atomic per row per wave)
#pragma unroll
    for (int k = 0; k < 4; k++) atomicAdd(&srow[k * 64 + lane], accr[k]);
    __syncthreads();

    // flush to global
    atomicAdd(&adj[base + it * TSZ + tid], srow[tid]);
    if (it != jt) {
        atomicAdd(&adj[base + jt * TSZ + tid], scol[tid]);
    }
}

// Kernel 2: per batch, softmax(adjusted) then weighted sum of boxes -> 4 outputs.
#define FBLK 1024
__global__ __launch_bounds__(FBLK) void soft_nms_finish_kernel(
    const void* __restrict__ boxes_raw,  // (B,N,4) f32 or bf16
    const float* __restrict__ adj,       // (B,N)   f32
    void* __restrict__ out)              // (B,4)   dtype matches input
{
    constexpr int K  = NBOX / FBLK;             // 8 items per thread
    constexpr int NW = FBLK / 64;               // 16 waves
    const int b   = blockIdx.x;
    const int tid = threadIdx.x;
    const float* ab = adj + (size_t)b * NBOX;
    const size_t boxbase = (size_t)b * NBOX;

    const bool isf32 = wave_probe_is_f32(boxes_raw);

    float av[K];
    float m = -3.4e38f;
#pragma unroll
    for (int k = 0; k < K; k++) {
        av[k] = ab[k * FBLK + tid];
        m = fmaxf(m, av[k]);
    }
#pragma unroll
    for (int off = 32; off > 0; off >>= 1)
        m = fmaxf(m, __shfl_down(m, off));

    __shared__ float smax[NW];
    if ((tid & 63) == 0) smax[tid >> 6] = m;
    __syncthreads();
    float M = smax[0];
#pragma unroll
    for (int w = 1; w < NW; w++) M = fmaxf(M, smax[w]);

    const float L2E = 1.4426950408889634f;
    float es = 0.0f, s0 = 0.0f, s1 = 0.0f, s2 = 0.0f, s3 = 0.0f;
#pragma unroll
    for (int k = 0; k < K; k++) {
        const float e = __builtin_amdgcn_exp2f((av[k] - M) * L2E);
        const float4 u = load_box(boxes_raw, boxbase + k * FBLK + tid, isf32);
        es += e;
        s0 += e * u.x;
        s1 += e * u.y;
        s2 += e * u.z;
        s3 += e * u.w;
    }
#pragma unroll
    for (int off = 32; off > 0; off >>= 1) {
        es += __shfl_down(es, off);
        s0 += __shfl_down(s0, off);
        s1 += __shfl_down(s1, off);
        s2 += __shfl_down(s2, off);
        s3 += __shfl_down(s3, off);
    }
    __shared__ float sred[NW][5];
    if ((tid & 63) == 0) {
        const int w = tid >> 6;
        sred[w][0] = es; sred[w][1] = s0; sred[w][2] = s1;
        sred[w][3] = s2; sred[w][4] = s3;
    }
    __syncthreads();
    if (tid == 0) {
        float ES = 0.0f, o[4] = {0.0f, 0.0f, 0.0f, 0.0f};
#pragma unroll
        for (int w = 0; w < NW; w++) {
            ES   += sred[w][0];
            o[0] += sred[w][1];
            o[1] += sred[w][2];
            o[2] += sred[w][3];
            o[3] += sred[w][4];
        }
        const float inv = 1.0f / ES;
        if (isf32) {
            float* of = (float*)out;
            for (int c = 0; c < 4; c++) of[b * 4 + c] = o[c] * inv;
        } else {
            __hip_bfloat16* oh = (__hip_bfloat16*)out;
            for (int c = 0; c < 4; c++) oh[b * 4 + c] = __float2bfloat16(o[c] * inv);
        }
    }
}

extern "C" void kernel_launch(void* const* d_in, const int* in_sizes, int n_in,
                              void* d_out, int out_size, void* d_ws, size_t ws_size,
                              hipStream_t stream) {
    const void* boxes_raw  = d_in[0];   // (4,8192,4)
    const void* scores_raw = d_in[1];   // (4,8192)
    float* adj = (float*)d_ws;          // (4,8192) f32 scratch

    hipMemsetAsync(adj, 0, (size_t)BATCH * NBOX * sizeof(float), stream);
    soft_nms_adj_kernel<<<dim3(BATCH * NPAIRS), dim3(BLOCK), 0, stream>>>(
        boxes_raw, scores_raw, adj);
    soft_nms_finish_kernel<<<dim3(BATCH), dim3(FBLK), 0, stream>>>(boxes_raw, adj, d_out);
}

// Round 9
// 148.766 us; speedup vs baseline: 1.8254x; 1.8254x over previous
//
#include <hip/hip_runtime.h>
#include <hip/hip_bf16.h>

#define BATCH   4
#define NBOX    8192
#define BLOCK   256
#define TSZ     256                  // tile size (rows & cols)
#define NT      (NBOX / TSZ)         // 32 tiles per batch
#define NPAIRS  (NT * (NT + 1) / 2)  // 528 tile-pairs per batch
#define PART_ELEMS ((size_t)BATCH * NT * NT * TSZ)   // 1M floats = 4 MB

__device__ __forceinline__ float bf2f(unsigned short u) {
    union { unsigned int i; float f; } c;
    c.i = ((unsigned int)u) << 16;
    return c.f;
}

__device__ __forceinline__ bool box_plausible(float x1, float y1, float x2, float y2) {
    bool ok = (x1 == x1) && (y1 == y1) && (x2 == x2) && (y2 == y2);
    ok = ok && fabsf(x1) < 1e4f && fabsf(y1) < 1e4f && fabsf(x2) < 1e4f && fabsf(y2) < 1e4f;
    ok = ok && x1 >= -1.0f && x1 <= 300.0f && y1 >= -1.0f && y1 <= 300.0f;
    const float w = x2 - x1, h = y2 - y1;
    ok = ok && w >= -0.1f && w <= 80.0f && h >= -0.1f && h <= 80.0f;
    return ok;
}

// Wave-redundant dtype probe; all waves deterministically agree. true -> f32.
__device__ __forceinline__ bool wave_probe_is_f32(const void* boxes_raw) {
    const int lane = threadIdx.x & 63;
    const float* bf = (const float*)boxes_raw;
    const bool okf = box_plausible(bf[lane * 4 + 0], bf[lane * 4 + 1],
                                   bf[lane * 4 + 2], bf[lane * 4 + 3]);
    const unsigned short* bh = (const unsigned short*)boxes_raw;
    const bool okh = box_plausible(bf2f(bh[lane * 4 + 0]), bf2f(bh[lane * 4 + 1]),
                                   bf2f(bh[lane * 4 + 2]), bf2f(bh[lane * 4 + 3]));
    const unsigned long long mf = __ballot(okf);
    const unsigned long long mh = __ballot(okh);
    return __popcll(mf) >= __popcll(mh);
}

__device__ __forceinline__ float4 load_box(const void* boxes_raw, size_t idx, bool isf32) {
    if (isf32) {
        return reinterpret_cast<const float4*>(boxes_raw)[idx];
    } else {
        const ushort4 u = reinterpret_cast<const ushort4*>(boxes_raw)[idx];
        return make_float4(bf2f(u.x), bf2f(u.y), bf2f(u.z), bf2f(u.w));
    }
}

__device__ __forceinline__ float load_score(const void* scores_raw, size_t idx, bool isf32) {
    return isf32 ? ((const float*)scores_raw)[idx]
                 : bf2f(((const unsigned short*)scores_raw)[idx]);
}

// exp(-iou/0.5) = exp2(iou * (-2 log2 e)); arg in [-2.886, 0] -> raw v_exp ok
#define CEXP (-2.8853900817779268f)

__device__ __forceinline__ float pair_weight(
    float ix1, float iy1, float ix2, float iy2, float iarea,
    const float4& bj, float jarea)
{
    float w = fminf(ix2, bj.z) - fmaxf(ix1, bj.x);
    float h = fminf(iy2, bj.w) - fmaxf(iy1, bj.y);
    w = fmaxf(w, 0.0f);
    h = fmaxf(h, 0.0f);
    const float inter = w * h;
    const float uni   = iarea + jarea - inter;          // >= ~1 always
    const float arg   = (CEXP * inter) * __builtin_amdgcn_rcpf(uni);
    return __builtin_amdgcn_exp2f(arg);
}

// Symmetric tile-pair kernel (round-7 hot loop, unchanged). Epilogue:
// USE_PART=true  -> race-free plain stores into part[b][T][p][idx] (every slot
//                   written exactly once: p>=T by row side of block (T,p),
//                   p<T by col side of block (p,T)); no memset needed.
// USE_PART=false -> round-7 atomicAdd into pre-zeroed adj (ws too small).
template <bool USE_PART>
__global__ __launch_bounds__(BLOCK, 4) void soft_nms_adj_kernel(
    const void* __restrict__ boxes_raw,   // (B,N,4) f32 or bf16
    const void* __restrict__ scores_raw,  // (B,N)   f32 or bf16
    float* __restrict__ dst)              // part (B,NT,NT,TSZ) or adj (B,N)
{
    __shared__ float4 sbox[TSZ];          // j-tile: x1,y1,x2,y2
    __shared__ float2 sas[TSZ];           // j-tile: area, score
    __shared__ float  srow[4][TSZ];       // per-wave row partials

    const int bid = blockIdx.x;
    const int b   = bid / NPAIRS;
    int p = bid % NPAIRS;
    int it = 0;
    while (p >= NT - it) { p -= NT - it; it++; }   // triangular decode
    const int jt = it + p;

    const int tid  = threadIdx.x;
    const int lane = tid & 63;
    const int wv   = tid >> 6;

    const bool isf32 = wave_probe_is_f32(boxes_raw);
    const size_t base = (size_t)b * NBOX;

    // stage j-tile into LDS
    {
        const int jg = jt * TSZ + tid;
        const float4 uj = load_box(boxes_raw, base + jg, isf32);
        sbox[tid] = uj;
        sas[tid]  = make_float2((uj.z - uj.x) * (uj.w - uj.y),
                                load_score(scores_raw, base + jg, isf32));
    }

    // rows: thread owns rows {k*64 + lane} of the i-tile (same set in every wave)
    float rx1[4], ry1[4], rx2[4], ry2[4], rar[4], rsc[4], accr[4];
#pragma unroll
    for (int k = 0; k < 4; k++) {
        const int ig = it * TSZ + k * 64 + lane;
        const float4 ui = load_box(boxes_raw, base + ig, isf32);
        rx1[k] = ui.x; ry1[k] = ui.y; rx2[k] = ui.z; ry2[k] = ui.w;
        rar[k] = (ui.z - ui.x) * (ui.w - ui.y);
        rsc[k] = load_score(scores_raw, base + ig, isf32);
        accr[k] = 0.0f;
    }

    __syncthreads();

    float accc = 0.0f;   // col partial for col (wv*64 + lane) == tid

    if (it == jt) {
        // diagonal: full ordered pairs, row side only (includes i==j)
#pragma unroll 2
        for (int t = 0; t < 64; t++) {
            const int idx = wv * 64 + ((lane + t) & 63);
            const float4 bj = sbox[idx];
            const float2 as = sas[idx];
#pragma unroll
            for (int k = 0; k < 4; k++) {
                const float e = pair_weight(rx1[k], ry1[k], rx2[k], ry2[k], rar[k], bj, as.x);
                accr[k] = fmaf(e, as.y, accr[k]);
            }
        }
    } else {
        // off-diagonal: symmetric; col accumulator rides in registers per lane
#pragma unroll 2
        for (int t = 0; t < 64; t++) {
            const int idx = wv * 64 + ((lane + t) & 63);
            const float4 bj = sbox[idx];       // stride-1 window: conflict-free
            const float2 as = sas[idx];
            const float e0 = pair_weight(rx1[0], ry1[0], rx2[0], ry2[0], rar[0], bj, as.x);
            const float e1 = pair_weight(rx1[1], ry1[1], rx2[1], ry2[1], rar[1], bj, as.x);
            const float e2 = pair_weight(rx1[2], ry1[2], rx2[2], ry2[2], rar[2], bj, as.x);
            const float e3 = pair_weight(rx1[3], ry1[3], rx2[3], ry2[3], rar[3], bj, as.x);
            accr[0] = fmaf(e0, as.y, accr[0]);
            accr[1] = fmaf(e1, as.y, accr[1]);
            accr[2] = fmaf(e2, as.y, accr[2]);
            accr[3] = fmaf(e3, as.y, accr[3]);
            const float c = fmaf(e0, rsc[0], fmaf(e1, rsc[1], fmaf(e2, rsc[2], e3 * rsc[3])));
            accc += __shfl(c, (lane - t) & 63);    // owner lane (lane+t)&63 pulls
        }
    }

    // combine row partials across the 4 waves via LDS
#pragma unroll
    for (int k = 0; k < 4; k++) srow[wv][k * 64 + lane] = accr[k];
    __syncthreads();
    const float rs = srow[0][tid] + srow[1][tid] + srow[2][tid] + srow[3][tid];

    if (USE_PART) {
        // row side -> part[b][it][jt][tid]; col side -> part[b][jt][it][tid]
        dst[(((size_t)b * NT + it) * NT + jt) * TSZ + tid] = rs;
        if (it != jt)
            dst[(((size_t)b * NT + jt) * NT + it) * TSZ + tid] = accc;
    } else {
        atomicAdd(&dst[base + it * TSZ + tid], rs);
        if (it != jt)
            atomicAdd(&dst[base + jt * TSZ + tid], accc);
    }
}

// Finish: reduce 32 partials per row (USE_PART) or read adj directly, then
// per-batch softmax + weighted box sum -> 4 outputs.
#define FBLK 1024
template <bool USE_PART>
__global__ __launch_bounds__(FBLK) void soft_nms_finish_kernel(
    const void* __restrict__ boxes_raw,  // (B,N,4) f32 or bf16
    const float* __restrict__ src,       // part (B,NT,NT,TSZ) or adj (B,N)
    void* __restrict__ out)              // (B,4)   dtype matches input
{
    constexpr int K  = NBOX / FBLK;             // 8 items per thread
    constexpr int NW = FBLK / 64;               // 16 waves
    const int b   = blockIdx.x;
    const int tid = threadIdx.x;
    const size_t boxbase = (size_t)b * NBOX;

    const bool isf32 = wave_probe_is_f32(boxes_raw);

    float av[K];
    float m = -3.4e38f;
#pragma unroll
    for (int k = 0; k < K; k++) {
        const int r = k * FBLK + tid;
        if (USE_PART) {
            const int T = r >> 8, idx = r & 255;
            const float* pp = src + (((size_t)b * NT + T) * NT) * TSZ + idx;
            float s = 0.0f;
#pragma unroll
            for (int q = 0; q < NT; q++) s += pp[q * TSZ];
            av[k] = s;
        } else {
            av[k] = src[boxbase + r];
        }
        m = fmaxf(m, av[k]);
    }
#pragma unroll
    for (int off = 32; off > 0; off >>= 1)
        m = fmaxf(m, __shfl_down(m, off));

    __shared__ float smax[NW];
    if ((tid & 63) == 0) smax[tid >> 6] = m;
    __syncthreads();
    float M = smax[0];
#pragma unroll
    for (int w = 1; w < NW; w++) M = fmaxf(M, smax[w]);

    const float L2E = 1.4426950408889634f;
    float es = 0.0f, s0 = 0.0f, s1 = 0.0f, s2 = 0.0f, s3 = 0.0f;
#pragma unroll
    for (int k = 0; k < K; k++) {
        const float e = __builtin_amdgcn_exp2f((av[k] - M) * L2E);
        const float4 u = load_box(boxes_raw, boxbase + k * FBLK + tid, isf32);
        es += e;
        s0 += e * u.x;
        s1 += e * u.y;
        s2 += e * u.z;
        s3 += e * u.w;
    }
#pragma unroll
    for (int off = 32; off > 0; off >>= 1) {
        es += __shfl_down(es, off);
        s0 += __shfl_down(s0, off);
        s1 += __shfl_down(s1, off);
        s2 += __shfl_down(s2, off);
        s3 += __shfl_down(s3, off);
    }
    __shared__ float sred[NW][5];
    if ((tid & 63) == 0) {
        const int w = tid >> 6;
        sred[w][0] = es; sred[w][1] = s0; sred[w][2] = s1;
        sred[w][3] = s2; sred[w][4] = s3;
    }
    __syncthreads();
    if (tid == 0) {
        float ES = 0.0f, o[4] = {0.0f, 0.0f, 0.0f, 0.0f};
#pragma unroll
        for (int w = 0; w < NW; w++) {
            ES   += sred[w][0];
            o[0] += sred[w][1];
            o[1] += sred[w][2];
            o[2] += sred[w][3];
            o[3] += sred[w][4];
        }
        const float inv = 1.0f / ES;
        if (isf32) {
            float* of = (float*)out;
            for (int c = 0; c < 4; c++) of[b * 4 + c] = o[c] * inv;
        } else {
            __hip_bfloat16* oh = (__hip_bfloat16*)out;
            for (int c = 0; c < 4; c++) oh[b * 4 + c] = __float2bfloat16(o[c] * inv);
        }
    }
}

extern "C" void kernel_launch(void* const* d_in, const int* in_sizes, int n_in,
                              void* d_out, int out_size, void* d_ws, size_t ws_size,
                              hipStream_t stream) {
    const void* boxes_raw  = d_in[0];   // (4,8192,4)
    const void* scores_raw = d_in[1];   // (4,8192)

    if (ws_size >= PART_ELEMS * sizeof(float)) {
        // main path: 2 dispatches, no memset, no global atomics
        float* part = (float*)d_ws;     // (B,NT,NT,TSZ) = 4 MB
        soft_nms_adj_kernel<true><<<dim3(BATCH * NPAIRS), dim3(BLOCK), 0, stream>>>(
            boxes_raw, scores_raw, part);
        soft_nms_finish_kernel<true><<<dim3(BATCH), dim3(FBLK), 0, stream>>>(
            boxes_raw, part, d_out);
    } else {
        // fallback: proven round-7 path
        float* adj = (float*)d_ws;      // (4,8192) f32 scratch
        hipMemsetAsync(adj, 0, (size_t)BATCH * NBOX * sizeof(float), stream);
        soft_nms_adj_kernel<false><<<dim3(BATCH * NPAIRS), dim3(BLOCK), 0, stream>>>(
            boxes_raw, scores_raw, adj);
        soft_nms_finish_kernel<false><<<dim3(BATCH), dim3(FBLK), 0, stream>>>(
            boxes_raw, adj, d_out);
    }
}

// Round 10
// 137.017 us; speedup vs baseline: 1.9819x; 1.0858x over previous
//
#include <hip/hip_runtime.h>
#include <hip/hip_bf16.h>

#define BATCH   4
#define NBOX    8192
#define BLOCK   256
#define TSZ     256                  // tile size (rows & cols)
#define NT      (NBOX / TSZ)         // 32 tiles per batch
#define NPAIRS  (NT * (NT + 1) / 2)  // 528 tile-pairs per batch

__device__ __forceinline__ float bf2f(unsigned short u) {
    union { unsigned int i; float f; } c;
    c.i = ((unsigned int)u) << 16;
    return c.f;
}

__device__ __forceinline__ bool box_plausible(float x1, float y1, float x2, float y2) {
    bool ok = (x1 == x1) && (y1 == y1) && (x2 == x2) && (y2 == y2);
    ok = ok && fabsf(x1) < 1e4f && fabsf(y1) < 1e4f && fabsf(x2) < 1e4f && fabsf(y2) < 1e4f;
    ok = ok && x1 >= -1.0f && x1 <= 300.0f && y1 >= -1.0f && y1 <= 300.0f;
    const float w = x2 - x1, h = y2 - y1;
    ok = ok && w >= -0.1f && w <= 80.0f && h >= -0.1f && h <= 80.0f;
    return ok;
}

// Wave-redundant dtype probe; all waves deterministically agree. true -> f32.
__device__ __forceinline__ bool wave_probe_is_f32(const void* boxes_raw) {
    const int lane = threadIdx.x & 63;
    const float* bf = (const float*)boxes_raw;
    const bool okf = box_plausible(bf[lane * 4 + 0], bf[lane * 4 + 1],
                                   bf[lane * 4 + 2], bf[lane * 4 + 3]);
    const unsigned short* bh = (const unsigned short*)boxes_raw;
    const bool okh = box_plausible(bf2f(bh[lane * 4 + 0]), bf2f(bh[lane * 4 + 1]),
                                   bf2f(bh[lane * 4 + 2]), bf2f(bh[lane * 4 + 3]));
    const unsigned long long mf = __ballot(okf);
    const unsigned long long mh = __ballot(okh);
    return __popcll(mf) >= __popcll(mh);
}

__device__ __forceinline__ float4 load_box(const void* boxes_raw, size_t idx, bool isf32) {
    if (isf32) {
        return reinterpret_cast<const float4*>(boxes_raw)[idx];
    } else {
        const ushort4 u = reinterpret_cast<const ushort4*>(boxes_raw)[idx];
        return make_float4(bf2f(u.x), bf2f(u.y), bf2f(u.z), bf2f(u.w));
    }
}

__device__ __forceinline__ float load_score(const void* scores_raw, size_t idx, bool isf32) {
    return isf32 ? ((const float*)scores_raw)[idx]
                 : bf2f(((const unsigned short*)scores_raw)[idx]);
}

// exp(-iou/0.5) = exp2(iou * (-2 log2 e)); arg in [-2.886, 0] -> raw v_exp ok
#define CEXP (-2.8853900817779268f)

__device__ __forceinline__ float pair_weight(
    float ix1, float iy1, float ix2, float iy2, float iarea,
    const float4& bj, float jarea)
{
    float w = fminf(ix2, bj.z) - fmaxf(ix1, bj.x);
    float h = fminf(iy2, bj.w) - fmaxf(iy1, bj.y);
    w = fmaxf(w, 0.0f);
    h = fmaxf(h, 0.0f);
    const float inter = w * h;
    const float uni   = iarea + jarea - inter;          // >= ~1 always
    const float arg   = (CEXP * inter) * __builtin_amdgcn_rcpf(uni);
    return __builtin_amdgcn_exp2f(arg);
}

// adjusted[b][i] = sum_j exp(-2*iou(i,j)) * scores[b][j], exploiting symmetry.
// Round-7 structure + explicit software pipelining in the t-loop:
//  - sbox/sas for step t+1 prefetched before computing step t
//  - the shfl (ds_bpermute) result is consumed one iteration late, so its
//    LDS round-trip is hidden behind a full step of independent VALU work.
__global__ __launch_bounds__(BLOCK, 4) void soft_nms_adj_kernel(
    const void* __restrict__ boxes_raw,   // (B,N,4) f32 or bf16
    const void* __restrict__ scores_raw,  // (B,N)   f32 or bf16
    float* __restrict__ adj)              // (B,N)   f32, zeroed
{
    __shared__ float4 sbox[TSZ];          // j-tile: x1,y1,x2,y2
    __shared__ float2 sas[TSZ];           // j-tile: area, score
    __shared__ float  srow[4][TSZ];       // per-wave row partials

    const int bid = blockIdx.x;
    const int b   = bid / NPAIRS;
    int p = bid % NPAIRS;
    int it = 0;
    while (p >= NT - it) { p -= NT - it; it++; }   // triangular decode
    const int jt = it + p;

    const int tid  = threadIdx.x;
    const int lane = tid & 63;
    const int wv   = tid >> 6;

    const bool isf32 = wave_probe_is_f32(boxes_raw);
    const size_t base = (size_t)b * NBOX;

    // stage j-tile into LDS
    {
        const int jg = jt * TSZ + tid;
        const float4 uj = load_box(boxes_raw, base + jg, isf32);
        sbox[tid] = uj;
        sas[tid]  = make_float2((uj.z - uj.x) * (uj.w - uj.y),
                                load_score(scores_raw, base + jg, isf32));
    }

    // rows: thread owns rows {k*64 + lane} of the i-tile (same set in every wave)
    float rx1[4], ry1[4], rx2[4], ry2[4], rar[4], rsc[4], accr[4];
#pragma unroll
    for (int k = 0; k < 4; k++) {
        const int ig = it * TSZ + k * 64 + lane;
        const float4 ui = load_box(boxes_raw, base + ig, isf32);
        rx1[k] = ui.x; ry1[k] = ui.y; rx2[k] = ui.z; ry2[k] = ui.w;
        rar[k] = (ui.z - ui.x) * (ui.w - ui.y);
        rsc[k] = load_score(scores_raw, base + ig, isf32);
        accr[k] = 0.0f;
    }

    __syncthreads();

    const int wvbase = wv * 64;

    if (it == jt) {
        // diagonal: full ordered pairs, row side only (includes i==j)
        int rot = lane;
        float4 bj = sbox[wvbase + rot];
        float2 as = sas[wvbase + rot];
#pragma unroll 4
        for (int t = 0; t < 64; t++) {
            const int nrot = (rot + 1) & 63;
            const float4 bjn = sbox[wvbase + nrot];   // prefetch t+1 (wrap read ok)
            const float2 asn = sas[wvbase + nrot];
#pragma unroll
            for (int k = 0; k < 4; k++) {
                const float e = pair_weight(rx1[k], ry1[k], rx2[k], ry2[k], rar[k], bj, as.x);
                accr[k] = fmaf(e, as.y, accr[k]);
            }
            rot = nrot; bj = bjn; as = asn;
        }
    } else {
        // off-diagonal: symmetric; col accumulator rides in registers per lane.
        // g carries the previous step's shfl result (consumed one iter late).
        int rot = lane;
        float4 bj = sbox[wvbase + rot];
        float2 as = sas[wvbase + rot];
        float accc = 0.0f;
        float g = 0.0f;
#pragma unroll 4
        for (int t = 0; t < 64; t++) {
            const int nrot = (rot + 1) & 63;
            const float4 bjn = sbox[wvbase + nrot];   // prefetch t+1 (wrap read ok)
            const float2 asn = sas[wvbase + nrot];
            const float e0 = pair_weight(rx1[0], ry1[0], rx2[0], ry2[0], rar[0], bj, as.x);
            const float e1 = pair_weight(rx1[1], ry1[1], rx2[1], ry2[1], rar[1], bj, as.x);
            const float e2 = pair_weight(rx1[2], ry1[2], rx2[2], ry2[2], rar[2], bj, as.x);
            const float e3 = pair_weight(rx1[3], ry1[3], rx2[3], ry2[3], rar[3], bj, as.x);
            accr[0] = fmaf(e0, as.y, accr[0]);
            accr[1] = fmaf(e1, as.y, accr[1]);
            accr[2] = fmaf(e2, as.y, accr[2]);
            accr[3] = fmaf(e3, as.y, accr[3]);
            const float c = fmaf(e0, rsc[0], fmaf(e1, rsc[1], fmaf(e2, rsc[2], e3 * rsc[3])));
            accc += g;                               // previous step's bpermute result
            g = __shfl(c, (lane - t) & 63);          // owner lane (lane+t)&63 pulls
            rot = nrot; bj = bjn; as = asn;
        }
        accc += g;                                   // drain the pipeline
        atomicAdd(&adj[base + jt * TSZ + wvbase + lane], accc);  // exclusive window
    }

    // combine row partials across the 4 waves via LDS, one atomic per row
#pragma unroll
    for (int k = 0; k < 4; k++) srow[wv][k * 64 + lane] = accr[k];
    __syncthreads();
    {
        const float rs = srow[0][tid] + srow[1][tid] + srow[2][tid] + srow[3][tid];
        atomicAdd(&adj[base + it * TSZ + tid], rs);
    }
}

// Kernel 2: per batch, softmax(adjusted) then weighted sum of boxes -> 4 outputs.
#define FBLK 1024
__global__ __launch_bounds__(FBLK) void soft_nms_finish_kernel(
    const void* __restrict__ boxes_raw,  // (B,N,4) f32 or bf16
    const float* __restrict__ adj,       // (B,N)   f32
    void* __restrict__ out)              // (B,4)   dtype matches input
{
    constexpr int K  = NBOX / FBLK;             // 8 items per thread
    constexpr int NW = FBLK / 64;               // 16 waves
    const int b   = blockIdx.x;
    const int tid = threadIdx.x;
    const float* ab = adj + (size_t)b * NBOX;
    const size_t boxbase = (size_t)b * NBOX;

    const bool isf32 = wave_probe_is_f32(boxes_raw);

    float av[K];
    float m = -3.4e38f;
#pragma unroll
    for (int k = 0; k < K; k++) {
        av[k] = ab[k * FBLK + tid];
        m = fmaxf(m, av[k]);
    }
#pragma unroll
    for (int off = 32; off > 0; off >>= 1)
        m = fmaxf(m, __shfl_down(m, off));

    __shared__ float smax[NW];
    if ((tid & 63) == 0) smax[tid >> 6] = m;
    __syncthreads();
    float M = smax[0];
#pragma unroll
    for (int w = 1; w < NW; w++) M = fmaxf(M, smax[w]);

    const float L2E = 1.4426950408889634f;
    float es = 0.0f, s0 = 0.0f, s1 = 0.0f, s2 = 0.0f, s3 = 0.0f;
#pragma unroll
    for (int k = 0; k < K; k++) {
        const float e = __builtin_amdgcn_exp2f((av[k] - M) * L2E);
        const float4 u = load_box(boxes_raw, boxbase + k * FBLK + tid, isf32);
        es += e;
        s0 += e * u.x;
        s1 += e * u.y;
        s2 += e * u.z;
        s3 += e * u.w;
    }
#pragma unroll
    for (int off = 32; off > 0; off >>= 1) {
        es += __shfl_down(es, off);
        s0 += __shfl_down(s0, off);
        s1 += __shfl_down(s1, off);
        s2 += __shfl_down(s2, off);
        s3 += __shfl_down(s3, off);
    }
    __shared__ float sred[NW][5];
    if ((tid & 63) == 0) {
        const int w = tid >> 6;
        sred[w][0] = es; sred[w][1] = s0; sred[w][2] = s1;
        sred[w][3] = s2; sred[w][4] = s3;
    }
    __syncthreads();
    if (tid == 0) {
        float ES = 0.0f, o[4] = {0.0f, 0.0f, 0.0f, 0.0f};
#pragma unroll
        for (int w = 0; w < NW; w++) {
            ES   += sred[w][0];
            o[0] += sred[w][1];
            o[1] += sred[w][2];
            o[2] += sred[w][3];
            o[3] += sred[w][4];
        }
        const float inv = 1.0f / ES;
        if (isf32) {
            float* of = (float*)out;
            for (int c = 0; c < 4; c++) of[b * 4 + c] = o[c] * inv;
        } else {
            __hip_bfloat16* oh = (__hip_bfloat16*)out;
            for (int c = 0; c < 4; c++) oh[b * 4 + c] = __float2bfloat16(o[c] * inv);
        }
    }
}

extern "C" void kernel_launch(void* const* d_in, const int* in_sizes, int n_in,
                              void* d_out, int out_size, void* d_ws, size_t ws_size,
                              hipStream_t stream) {
    const void* boxes_raw  = d_in[0];   // (4,8192,4)
    const void* scores_raw = d_in[1];   // (4,8192)
    float* adj = (float*)d_ws;          // (4,8192) f32 scratch

    hipMemsetAsync(adj, 0, (size_t)BATCH * NBOX * sizeof(float), stream);
    soft_nms_adj_kernel<<<dim3(BATCH * NPAIRS), dim3(BLOCK), 0, stream>>>(
        boxes_raw, scores_raw, adj);
    soft_nms_finish_kernel<<<dim3(BATCH), dim3(FBLK), 0, stream>>>(boxes_raw, adj, d_out);
}